// Round 2
// baseline (605.373 us; speedup 1.0000x reference)
//
#include <hip/hip_runtime.h>
#include <hip/hip_bf16.h>
#include <cstdint>
#include <cstddef>

#define H_     8
#define KV_    4
#define D_     256
#define HID_   2560
#define S_     32
#define L_     8192
#define NQ_    64          // G*S query rows per kv head
#define LKEEP_ (L_ - S_)   // 8160

// ---------------- Kernel A: QKV projection, atomic K-split ----------------
// qkv[32][4096] (cols 0..2047 Wq, 2048..3071 Wk, 3072..4095 Wv), zero-initialized.
// grid (8 col-tiles of 512, 128 k-splits of 20), block 256.
// Thread: 2 cols x 32 rows. W read exactly once, 512B/wave coalesced loads.
__global__ __launch_bounds__(256) void k_qkv(
    const float* __restrict__ hidden,
    const float* __restrict__ Wq, const float* __restrict__ Wk, const float* __restrict__ Wv,
    float* __restrict__ qkv)
{
    const int col0  = blockIdx.x * 512;
    const int kbase = blockIdx.y * 20;       // 128 * 20 = 2560
    const float* W; int ldw, wb;
    if (col0 < 2048)      { W = Wq; ldw = 2048; wb = col0; }
    else if (col0 < 3072) { W = Wk; ldw = 1024; wb = col0 - 2048; }
    else                  { W = Wv; ldw = 1024; wb = col0 - 3072; }
    const int tid = threadIdx.x;
    const int tc  = tid * 2;                 // 0..510 within tile

    __shared__ __align__(16) float hs[20][36];   // [k][row], row stride 144B (16B aligned)
    // stage hidden chunk [32 rows][20 k] transposed
    for (int i = 0; i < 3; i++) {
        int idx = i * 256 + tid;
        if (idx < 640) {
            int r = idx / 20, k = idx % 20;
            hs[k][r] = hidden[r * HID_ + kbase + k];
        }
    }
    __syncthreads();

    float acc[32][2] = {};
    #pragma unroll 4
    for (int k = 0; k < 20; k++) {
        float2 w2 = *(const float2*)&W[(size_t)(kbase + k) * ldw + wb + tc];
        #pragma unroll
        for (int r4 = 0; r4 < 8; r4++) {
            float4 h = *(const float4*)&hs[k][r4 * 4];
            acc[r4*4+0][0] = fmaf(h.x, w2.x, acc[r4*4+0][0]); acc[r4*4+0][1] = fmaf(h.x, w2.y, acc[r4*4+0][1]);
            acc[r4*4+1][0] = fmaf(h.y, w2.x, acc[r4*4+1][0]); acc[r4*4+1][1] = fmaf(h.y, w2.y, acc[r4*4+1][1]);
            acc[r4*4+2][0] = fmaf(h.z, w2.x, acc[r4*4+2][0]); acc[r4*4+2][1] = fmaf(h.z, w2.y, acc[r4*4+2][1]);
            acc[r4*4+3][0] = fmaf(h.w, w2.x, acc[r4*4+3][0]); acc[r4*4+3][1] = fmaf(h.w, w2.y, acc[r4*4+3][1]);
        }
    }
    #pragma unroll
    for (int r = 0; r < 32; r++) {
        atomicAdd(&qkv[r * 4096 + col0 + tc],     acc[r][0]);
        atomicAdd(&qkv[r * 4096 + col0 + tc + 1], acc[r][1]);
    }
}

// ---------------- Kernel B: RMSNorm + RoPE ----------------
// grid 512 = 16 type-heads (8 q, 4 k, 4 v) x 32 seq
__global__ __launch_bounds__(256) void k_rms_rope(
    const float* __restrict__ qkv,
    const float* __restrict__ cosb, const float* __restrict__ sinb,
    const float* __restrict__ qw, const float* __restrict__ kw, const float* __restrict__ vw,
    float* __restrict__ q, float* __restrict__ kn, float* __restrict__ vn)
{
    const int b = blockIdx.x;
    const int th = b >> 5;     // 0..15
    const int s  = b & 31;
    const int d  = threadIdx.x;
    const float* w; float* op; int col; bool rope;
    if (th < 8)       { w = qw; col = th * 256;               op = q  + ((size_t)(th * 32 + s)) * 256;        rope = true;  }
    else if (th < 12) { w = kw; col = 2048 + (th - 8) * 256;  op = kn + ((size_t)((th - 8) * 32 + s)) * 256;  rope = true;  }
    else              { w = vw; col = 3072 + (th - 12) * 256; op = vn + ((size_t)((th - 12) * 32 + s)) * 256; rope = false; }
    float x = qkv[s * 4096 + col + d];
    float ss = x * x;
    #pragma unroll
    for (int m = 32; m; m >>= 1) ss += __shfl_xor(ss, m, 64);
    __shared__ float red[4];
    __shared__ float xs[256];
    if ((threadIdx.x & 63) == 0) red[threadIdx.x >> 6] = ss;
    __syncthreads();
    float tot = red[0] + red[1] + red[2] + red[3];
    float xn = x * rsqrtf(tot * (1.0f / 256.0f) + 1e-6f) * w[d];
    xs[d] = xn;
    __syncthreads();
    float out = xn;
    if (rope) {
        float rot = (d < 128) ? -xs[d + 128] : xs[d - 128];
        out = xn * cosb[s * 256 + d] + rot * sinb[s * 256 + d];
    }
    op[d] = out;
}

// ---------------- Kernel C: logits init = mask broadcast ----------------
// logits[kh][n][l] = mask[n&31][l]; grid 2048 x 256, float4 per thread
__global__ __launch_bounds__(256) void k_maskinit(
    const float* __restrict__ mask, float* __restrict__ logits)
{
    int idx4 = (blockIdx.x * 256 + threadIdx.x) * 4;   // over 2M floats
    int l = idx4 & (L_ - 1);
    int row = idx4 >> 13;
    int s = row & 31;
    *(float4*)&logits[idx4] = *(const float4*)&mask[s * L_ + l];
}

// ---------------- Kernel D: QK^T, atomic d-split x4 ----------------
// grid (32 L-tiles of 256, 4 kv, 4 d-splits of 64), block 512 (8 waves)
// Thread: 8 q-rows (wave-uniform -> LDS broadcast) x 4 keys.
__global__ __launch_bounds__(512) void k_qk(
    const float* __restrict__ qb,       // [KV][64][256]
    const float* __restrict__ cache_k,  // [KV][L][D]
    const float* __restrict__ knb,      // [KV][32][256]
    float* __restrict__ logits)
{
    const int l0 = blockIdx.x * 256;
    const int kh = blockIdx.y;
    const int d0base = blockIdx.z * 64;
    const int tid = threadIdx.x;
    const int r0 = (tid >> 6) * 8;      // wave-uniform 8 q-rows
    const int c0 = (tid & 63) * 4;      // 4 keys, 1KB/wave coalesced

    __shared__ __align__(16) float qs[32][68];    // [d][q]
    __shared__ __align__(16) float ks[32][260];   // [d][l]
    float acc[8][4] = {};

    for (int dc = 0; dc < 2; dc++) {
        const int d0 = d0base + dc * 32;
        // stage q-tile [64 q][32 d] -> qs[d][q]
        #pragma unroll
        for (int i = 0; i < 4; i++) {
            int idx = i * 512 + tid;            // 2048
            int n = idx >> 5, e = idx & 31;
            qs[e][n] = qb[((size_t)kh * 64 + n) * 256 + d0 + e];
        }
        // stage k-tile [256 l][32 d] -> ks[d][l] (rolled cache)
        #pragma unroll
        for (int i = 0; i < 4; i++) {
            int idx = i * 512 + tid;            // 2048 float4-groups = 8192 floats
            int l = idx >> 3, d4 = (idx & 7) * 4;
            int labs = l0 + l;
            const float* src = (labs < LKEEP_)
                ? (cache_k + ((size_t)kh * L_ + labs + S_) * 256 + d0 + d4)
                : (knb + ((size_t)kh * S_ + (labs - LKEEP_)) * 256 + d0 + d4);
            float4 v = *(const float4*)src;
            ks[d4 + 0][l] = v.x; ks[d4 + 1][l] = v.y;
            ks[d4 + 2][l] = v.z; ks[d4 + 3][l] = v.w;
        }
        __syncthreads();
        #pragma unroll 2
        for (int e = 0; e < 32; e++) {
            float4 k4 = *(const float4*)&ks[e][c0];
            float4 qa = *(const float4*)&qs[e][r0];
            float4 qc = *(const float4*)&qs[e][r0 + 4];
            float qv[8] = {qa.x, qa.y, qa.z, qa.w, qc.x, qc.y, qc.z, qc.w};
            #pragma unroll
            for (int i = 0; i < 8; i++) {
                acc[i][0] = fmaf(qv[i], k4.x, acc[i][0]);
                acc[i][1] = fmaf(qv[i], k4.y, acc[i][1]);
                acc[i][2] = fmaf(qv[i], k4.z, acc[i][2]);
                acc[i][3] = fmaf(qv[i], k4.w, acc[i][3]);
            }
        }
        __syncthreads();
    }
    #pragma unroll
    for (int i = 0; i < 8; i++)
        #pragma unroll
        for (int j = 0; j < 4; j++)
            atomicAdd(&logits[((size_t)kh * NQ_ + r0 + i) * L_ + l0 + c0 + j], acc[i][j]);
}

// ---------------- Kernel E: row stats (max + sum of exp) ----------------
__global__ __launch_bounds__(256) void k_rowstat(
    const float* __restrict__ logits,
    float* __restrict__ rowmax, float* __restrict__ rowsum)
{
    const int r = blockIdx.x;
    const int tid = threadIdx.x;
    const float* lp = logits + (size_t)r * L_;
    float m = -1e30f, s = 0.f;
    for (int i = tid; i < L_; i += 256) {
        float x = lp[i];
        float nm = fmaxf(m, x);
        s = s * __expf(m - nm) + __expf(x - nm);
        m = nm;
    }
    #pragma unroll
    for (int off = 32; off; off >>= 1) {
        float m2 = __shfl_xor(m, off, 64);
        float s2 = __shfl_xor(s, off, 64);
        float nm = fmaxf(m, m2);
        s = s * __expf(m - nm) + s2 * __expf(m2 - nm);
        m = nm;
    }
    __shared__ float rm[4], rs[4];
    if ((tid & 63) == 0) { rm[tid >> 6] = m; rs[tid >> 6] = s; }
    __syncthreads();
    if (tid == 0) {
        float M = fmaxf(fmaxf(rm[0], rm[1]), fmaxf(rm[2], rm[3]));
        float S = rs[0] * __expf(rm[0] - M) + rs[1] * __expf(rm[1] - M)
                + rs[2] * __expf(rm[2] - M) + rs[3] * __expf(rm[3] - M);
        rowmax[r] = M;
        rowsum[r] = S;
    }
}

// ---------------- Kernel F: PV, atomic L-split x128 ----------------
// grid (128 L-chunks of 64, 4 kv), block 512 (8 waves)
// Thread: 8 q-rows (wave-uniform broadcast) x 4 d-cols. exp applied at P staging.
__global__ __launch_bounds__(512) void k_pv(
    const float* __restrict__ logits,
    const float* __restrict__ rowmax,
    const float* __restrict__ cache_v, const float* __restrict__ vnb,
    float* __restrict__ pvacc)
{
    const int l0 = blockIdx.x * 64;
    const int kh = blockIdx.y;
    const int tid = threadIdx.x;
    const int r0 = (tid >> 6) * 8;      // wave-uniform 8 q-rows
    const int c0 = (tid & 63) * 4;      // 4 d-cols, 1KB/wave

    __shared__ __align__(16) float ps[64][68];    // [l][q] = exp(logit - rowmax)
    __shared__ __align__(16) float vs[16][260];   // [l][d]

    // stage P tile [64 l][64 q] with exp
    #pragma unroll
    for (int i = 0; i < 8; i++) {
        int idx = i * 512 + tid;        // 4096
        int l = idx & 63, q = idx >> 6;
        float x = logits[((size_t)kh * NQ_ + q) * L_ + l0 + l];
        ps[l][q] = __expf(x - rowmax[kh * NQ_ + q]);
    }

    float acc[8][4] = {};
    for (int lc = 0; lc < 4; lc++) {
        // stage V chunk [16 l][256 d]
        #pragma unroll
        for (int i = 0; i < 2; i++) {
            int idx = i * 512 + tid;    // 1024 float4-groups
            int l = idx >> 6, d4 = (idx & 63) * 4;
            int labs = l0 + lc * 16 + l;
            const float* src = (labs < LKEEP_)
                ? (cache_v + ((size_t)kh * L_ + labs + S_) * 256 + d4)
                : (vnb + ((size_t)kh * S_ + (labs - LKEEP_)) * 256 + d4);
            *(float4*)&vs[l][d4] = *(const float4*)src;
        }
        __syncthreads();
        #pragma unroll 4
        for (int l = 0; l < 16; l++) {
            float4 v4 = *(const float4*)&vs[l][c0];
            float4 pa = *(const float4*)&ps[lc * 16 + l][r0];
            float4 pb = *(const float4*)&ps[lc * 16 + l][r0 + 4];
            float pv[8] = {pa.x, pa.y, pa.z, pa.w, pb.x, pb.y, pb.z, pb.w};
            #pragma unroll
            for (int i = 0; i < 8; i++) {
                acc[i][0] = fmaf(pv[i], v4.x, acc[i][0]);
                acc[i][1] = fmaf(pv[i], v4.y, acc[i][1]);
                acc[i][2] = fmaf(pv[i], v4.z, acc[i][2]);
                acc[i][3] = fmaf(pv[i], v4.w, acc[i][3]);
            }
        }
        __syncthreads();
    }
    #pragma unroll
    for (int i = 0; i < 8; i++)
        #pragma unroll
        for (int j = 0; j < 4; j++)
            atomicAdd(&pvacc[((size_t)kh * NQ_ + r0 + i) * 256 + c0 + j], acc[i][j]);
}

// ---------------- Kernel G: normalize + head-interleave ----------------
// attn[s][h*256+d] = pvacc[kh][n][d] / rowsum
__global__ __launch_bounds__(256) void k_finish(
    const float* __restrict__ pvacc, const float* __restrict__ rowsum,
    float* __restrict__ attn)
{
    const int b = blockIdx.x;           // kh*64 + n
    const int kh = b >> 6, n = b & 63;
    const int d = threadIdx.x;
    const int h = kh * 2 + (n >> 5), s = n & 31;
    attn[(size_t)s * 2048 + h * 256 + d] = pvacc[(size_t)b * 256 + d] / rowsum[b];
}

// ---------------- Kernel H: W_o GEMM, atomic K-split into d_out ----------------
// grid (5 col-tiles of 512, 128 k-splits of 16), block 256
__global__ __launch_bounds__(256) void k_out(
    const float* __restrict__ attn, const float* __restrict__ Wo,
    float* __restrict__ out)
{
    const int col0  = blockIdx.x * 512;
    const int kbase = blockIdx.y * 16;      // 128 * 16 = 2048
    const int tid = threadIdx.x;
    const int tc  = tid * 2;

    __shared__ __align__(16) float hs[16][36];
    #pragma unroll
    for (int i = 0; i < 2; i++) {
        int idx = i * 256 + tid;            // 512 = 32r x 16k
        int r = idx >> 4, k = idx & 15;
        hs[k][r] = attn[r * 2048 + kbase + k];
    }
    __syncthreads();

    float acc[32][2] = {};
    #pragma unroll 4
    for (int k = 0; k < 16; k++) {
        float2 w2 = *(const float2*)&Wo[(size_t)(kbase + k) * 2560 + col0 + tc];
        #pragma unroll
        for (int r4 = 0; r4 < 8; r4++) {
            float4 h = *(const float4*)&hs[k][r4 * 4];
            acc[r4*4+0][0] = fmaf(h.x, w2.x, acc[r4*4+0][0]); acc[r4*4+0][1] = fmaf(h.x, w2.y, acc[r4*4+0][1]);
            acc[r4*4+1][0] = fmaf(h.y, w2.x, acc[r4*4+1][0]); acc[r4*4+1][1] = fmaf(h.y, w2.y, acc[r4*4+1][1]);
            acc[r4*4+2][0] = fmaf(h.z, w2.x, acc[r4*4+2][0]); acc[r4*4+2][1] = fmaf(h.z, w2.y, acc[r4*4+2][1]);
            acc[r4*4+3][0] = fmaf(h.w, w2.x, acc[r4*4+3][0]); acc[r4*4+3][1] = fmaf(h.w, w2.y, acc[r4*4+3][1]);
        }
    }
    #pragma unroll
    for (int r = 0; r < 32; r++) {
        atomicAdd(&out[r * 2560 + col0 + tc],     acc[r][0]);
        atomicAdd(&out[r * 2560 + col0 + tc + 1], acc[r][1]);
    }
}

// ---------------- host ----------------
extern "C" void kernel_launch(void* const* d_in, const int* in_sizes, int n_in,
                              void* d_out, int out_size, void* d_ws, size_t ws_size,
                              hipStream_t stream)
{
    const float* hidden  = (const float*)d_in[0];
    const float* cosb    = (const float*)d_in[1];
    const float* sinb    = (const float*)d_in[2];
    const float* cache_k = (const float*)d_in[3];
    const float* cache_v = (const float*)d_in[4];
    const float* mask    = (const float*)d_in[5];
    const float* Wq      = (const float*)d_in[6];
    const float* Wk      = (const float*)d_in[7];
    const float* Wv      = (const float*)d_in[8];
    const float* Wo      = (const float*)d_in[9];
    const float* qw      = (const float*)d_in[10];
    const float* kw      = (const float*)d_in[11];
    const float* vw      = (const float*)d_in[12];

    float* ws = (float*)d_ws;
    size_t off = 0;
    float* qkv    = ws + off; off += (size_t)32 * 4096;       // 131072
    float* qb     = ws + off; off += (size_t)KV_ * NQ_ * D_;  // 65536
    float* knb    = ws + off; off += (size_t)KV_ * S_ * D_;   // 32768
    float* vnb    = ws + off; off += (size_t)KV_ * S_ * D_;   // 32768
    float* logits = ws + off; off += (size_t)KV_ * NQ_ * L_;  // 2097152
    float* rowmax = ws + off; off += 256;
    float* rowsum = ws + off; off += 256;
    float* pvacc  = ws + off; off += (size_t)KV_ * NQ_ * D_;  // 65536
    float* attn   = ws + off; off += (size_t)S_ * H_ * D_;    // 65536

    hipMemsetAsync(qkv,   0, (size_t)131072 * 4, stream);
    hipMemsetAsync(pvacc, 0, (size_t)65536 * 4, stream);
    hipMemsetAsync(d_out, 0, (size_t)81920 * 4, stream);

    k_qkv<<<dim3(8, 128), 256, 0, stream>>>(hidden, Wq, Wk, Wv, qkv);
    k_rms_rope<<<512, 256, 0, stream>>>(qkv, cosb, sinb, qw, kw, vw, qb, knb, vnb);
    k_maskinit<<<2048, 256, 0, stream>>>(mask, logits);
    k_qk<<<dim3(32, 4, 4), 512, 0, stream>>>(qb, cache_k, knb, logits);
    k_rowstat<<<256, 256, 0, stream>>>(logits, rowmax, rowsum);
    k_pv<<<dim3(128, 4), 512, 0, stream>>>(logits, rowmax, cache_v, vnb, pvacc);
    k_finish<<<256, 256, 0, stream>>>(pvacc, rowsum, attn);
    k_out<<<dim3(5, 128), 256, 0, stream>>>(attn, Wo, (float*)d_out);
}

// Round 4
// 246.370 us; speedup vs baseline: 2.4572x; 2.4572x over previous
//
#include <hip/hip_runtime.h>
#include <hip/hip_bf16.h>
#include <cstdint>
#include <cstddef>

#define H_     8
#define KV_    4
#define D_     256
#define HID_   2560
#define S_     32
#define L_     8192
#define NQ_    64          // G*S query rows per kv head
#define LKEEP_ (L_ - S_)   // 8160

// ---------------- Kernel A: QKV projection, K-split x32 into partials ----------------
// part[32][32][4096]; cols 0..2047 Wq, 2048..3071 Wk, 3072..4095 Wv.
// grid (8 col-tiles of 512, 32 k-splits of 80), block 256.
// Race-free: each thread covers the FULL k-range of its split; partials by blockIdx.y.
__global__ __launch_bounds__(256) void k_qkv(
    const float* __restrict__ hidden,
    const float* __restrict__ Wq, const float* __restrict__ Wk, const float* __restrict__ Wv,
    float* __restrict__ part)
{
    const int col0  = blockIdx.x * 512;
    const int kbase = blockIdx.y * 80;
    const float* W; int ldw, wb;
    if (col0 < 2048)      { W = Wq; ldw = 2048; wb = col0; }
    else if (col0 < 3072) { W = Wk; ldw = 1024; wb = col0 - 2048; }
    else                  { W = Wv; ldw = 1024; wb = col0 - 3072; }
    const int tid = threadIdx.x;
    const int tc  = tid * 2;

    __shared__ __align__(16) float hsT[80][36];   // [k][row]
    for (int i = 0; i < 3; i++) {
        int idx = i * 256 + tid;
        if (idx < 640) {
            int r = idx / 20, c4 = idx % 20;
            float4 v = *(const float4*)&hidden[r * HID_ + kbase + c4 * 4];
            hsT[c4*4+0][r] = v.x; hsT[c4*4+1][r] = v.y;
            hsT[c4*4+2][r] = v.z; hsT[c4*4+3][r] = v.w;
        }
    }
    __syncthreads();

    const float* Wt = W + (size_t)kbase * ldw + wb + tc;
    float acc[32][2] = {};
#define LW(k) (*(const float2*)&Wt[(size_t)(k) * ldw])
#define FMABLK(k, wc) \
    _Pragma("unroll") for (int r4 = 0; r4 < 8; r4++) { \
      float4 h = *(const float4*)&hsT[(k)][r4*4]; \
      acc[r4*4+0][0] = fmaf(h.x, wc.x, acc[r4*4+0][0]); acc[r4*4+0][1] = fmaf(h.x, wc.y, acc[r4*4+0][1]); \
      acc[r4*4+1][0] = fmaf(h.y, wc.x, acc[r4*4+1][0]); acc[r4*4+1][1] = fmaf(h.y, wc.y, acc[r4*4+1][1]); \
      acc[r4*4+2][0] = fmaf(h.z, wc.x, acc[r4*4+2][0]); acc[r4*4+2][1] = fmaf(h.z, wc.y, acc[r4*4+2][1]); \
      acc[r4*4+3][0] = fmaf(h.w, wc.x, acc[r4*4+3][0]); acc[r4*4+3][1] = fmaf(h.w, wc.y, acc[r4*4+3][1]); }
#define STEPL(wreg, k) { float2 wc = wreg; wreg = LW((k) + 8); FMABLK(k, wc) }
#define STEPN(wreg, k) { float2 wc = wreg; FMABLK(k, wc) }

    float2 w0=LW(0),w1=LW(1),w2=LW(2),w3=LW(3),w4=LW(4),w5=LW(5),w6=LW(6),w7=LW(7);
    for (int ib = 0; ib <= 64; ib += 8) {     // k = 0..71 with prefetch k+8 <= 79
        STEPL(w0, ib+0) STEPL(w1, ib+1) STEPL(w2, ib+2) STEPL(w3, ib+3)
        STEPL(w4, ib+4) STEPL(w5, ib+5) STEPL(w6, ib+6) STEPL(w7, ib+7)
    }
    STEPN(w0, 72) STEPN(w1, 73) STEPN(w2, 74) STEPN(w3, 75)
    STEPN(w4, 76) STEPN(w5, 77) STEPN(w6, 78) STEPN(w7, 79)
#undef STEPL
#undef STEPN
#undef FMABLK
#undef LW
    float* op = part + (size_t)blockIdx.y * (32 * 4096);
    #pragma unroll
    for (int r = 0; r < 32; r++)
        *(float2*)&op[r * 4096 + col0 + tc] = make_float2(acc[r][0], acc[r][1]);
}

// ---------------- Kernel B: sum 32 partials + RMSNorm + RoPE ----------------
// grid 512 = 16 type-heads (8 q, 4 k, 4 v) x 32 seq
__global__ __launch_bounds__(256) void k_rms_rope(
    const float* __restrict__ part,
    const float* __restrict__ cosb, const float* __restrict__ sinb,
    const float* __restrict__ qw, const float* __restrict__ kw, const float* __restrict__ vw,
    float* __restrict__ q, float* __restrict__ kn, float* __restrict__ vn)
{
    const int b = blockIdx.x;
    const int th = b >> 5;     // 0..15
    const int s  = b & 31;
    const int d  = threadIdx.x;
    const float* w; float* op; int col; bool rope;
    if (th < 8)       { w = qw; col = th * 256;               op = q  + ((size_t)(th * 32 + s)) * 256;        rope = true;  }
    else if (th < 12) { w = kw; col = 2048 + (th - 8) * 256;  op = kn + ((size_t)((th - 8) * 32 + s)) * 256;  rope = true;  }
    else              { w = vw; col = 3072 + (th - 12) * 256; op = vn + ((size_t)((th - 12) * 32 + s)) * 256; rope = false; }
    const int base = s * 4096 + col + d;
    float a0 = 0.f, a1 = 0.f, a2 = 0.f, a3 = 0.f;
    #pragma unroll
    for (int p = 0; p < 32; p += 4) {
        a0 += part[(size_t)(p + 0) * 131072 + base];
        a1 += part[(size_t)(p + 1) * 131072 + base];
        a2 += part[(size_t)(p + 2) * 131072 + base];
        a3 += part[(size_t)(p + 3) * 131072 + base];
    }
    float x = (a0 + a1) + (a2 + a3);
    float ss = x * x;
    #pragma unroll
    for (int m = 32; m; m >>= 1) ss += __shfl_xor(ss, m, 64);
    __shared__ float red[4];
    __shared__ float xs[256];
    if ((threadIdx.x & 63) == 0) red[threadIdx.x >> 6] = ss;
    __syncthreads();
    float tot = red[0] + red[1] + red[2] + red[3];
    float xn = x * rsqrtf(tot * (1.0f / 256.0f) + 1e-6f) * w[d];
    xs[d] = xn;
    __syncthreads();
    float out = xn;
    if (rope) {
        float rot = (d < 128) ? -xs[d + 128] : xs[d - 128];
        out = xn * cosb[s * 256 + d] + rot * sinb[s * 256 + d];
    }
    op[d] = out;
}

// ---------------- Kernel C: QK^T + mask, block-owned tiles ----------------
// grid (64 l-tiles of 128, 4 kv), block 512. d looped in 8 chunks of 32, LDS double-buffered.
__global__ __launch_bounds__(512) void k_qk(
    const float* __restrict__ qb,       // [KV][64][256]
    const float* __restrict__ cache_k,  // [KV][L][D]
    const float* __restrict__ knb,      // [KV][32][256]
    const float* __restrict__ mask,     // [32][L]
    float* __restrict__ logits)         // [KV][64][L]
{
    const int l0 = blockIdx.x * 128;
    const int kh = blockIdx.y;
    const int tid = threadIdx.x;
    const int r0 = (tid >> 6) * 8;      // wave-uniform 8 q-rows
    const int c0 = (tid & 63) * 2;      // 2 keys per thread

    __shared__ __align__(16) float ks[2][32][132];   // [buf][d][l]
    __shared__ __align__(16) float qsq[2][64][36];   // [buf][q][d-chunk 32 +4 pad]

    float acc[8][2] = {};

    // stage chunk 0
    {
        int qq = tid >> 3, dq = tid & 7;
        *(float4*)&qsq[0][qq][dq * 4] =
            *(const float4*)&qb[((size_t)kh * 64 + qq) * 256 + dq * 4];
        #pragma unroll
        for (int i = 0; i < 2; i++) {
            int idx = i * 512 + tid;
            int l = idx >> 3, d4 = idx & 7;
            int labs = l0 + l;
            const float* src = (labs < LKEEP_)
                ? (cache_k + ((size_t)kh * L_ + labs + S_) * 256 + d4 * 4)
                : (knb + ((size_t)kh * S_ + (labs - LKEEP_)) * 256 + d4 * 4);
            float4 v = *(const float4*)src;
            ks[0][d4 * 4 + 0][l] = v.x; ks[0][d4 * 4 + 1][l] = v.y;
            ks[0][d4 * 4 + 2][l] = v.z; ks[0][d4 * 4 + 3][l] = v.w;
        }
    }
    __syncthreads();

    for (int dc = 0; dc < 8; dc++) {
        const int cur = dc & 1, nxt = cur ^ 1;
        if (dc < 7) {
            const int d0 = (dc + 1) * 32;
            {
                int qq = tid >> 3, dq = tid & 7;
                *(float4*)&qsq[nxt][qq][dq * 4] =
                    *(const float4*)&qb[((size_t)kh * 64 + qq) * 256 + d0 + dq * 4];
            }
            #pragma unroll
            for (int i = 0; i < 2; i++) {
                int idx = i * 512 + tid;
                int l = idx >> 3, d4 = idx & 7;
                int labs = l0 + l;
                const float* src = (labs < LKEEP_)
                    ? (cache_k + ((size_t)kh * L_ + labs + S_) * 256 + d0 + d4 * 4)
                    : (knb + ((size_t)kh * S_ + (labs - LKEEP_)) * 256 + d0 + d4 * 4);
                float4 v = *(const float4*)src;
                ks[nxt][d4 * 4 + 0][l] = v.x; ks[nxt][d4 * 4 + 1][l] = v.y;
                ks[nxt][d4 * 4 + 2][l] = v.z; ks[nxt][d4 * 4 + 3][l] = v.w;
            }
        }
        #pragma unroll
        for (int d4 = 0; d4 < 8; d4++) {
            float4 qv[8];
            #pragma unroll
            for (int i = 0; i < 8; i++)
                qv[i] = *(const float4*)&qsq[cur][r0 + i][d4 * 4];   // broadcast
            float2 k0 = *(const float2*)&ks[cur][d4 * 4 + 0][c0];
            float2 k1 = *(const float2*)&ks[cur][d4 * 4 + 1][c0];
            float2 k2 = *(const float2*)&ks[cur][d4 * 4 + 2][c0];
            float2 k3 = *(const float2*)&ks[cur][d4 * 4 + 3][c0];
            #pragma unroll
            for (int i = 0; i < 8; i++) {
                acc[i][0] = fmaf(qv[i].x, k0.x, acc[i][0]); acc[i][1] = fmaf(qv[i].x, k0.y, acc[i][1]);
                acc[i][0] = fmaf(qv[i].y, k1.x, acc[i][0]); acc[i][1] = fmaf(qv[i].y, k1.y, acc[i][1]);
                acc[i][0] = fmaf(qv[i].z, k2.x, acc[i][0]); acc[i][1] = fmaf(qv[i].z, k2.y, acc[i][1]);
                acc[i][0] = fmaf(qv[i].w, k3.x, acc[i][0]); acc[i][1] = fmaf(qv[i].w, k3.y, acc[i][1]);
            }
        }
        __syncthreads();
    }
    #pragma unroll
    for (int i = 0; i < 8; i++) {
        int qq = r0 + i, s = qq & 31;
        float2 m2 = *(const float2*)&mask[(size_t)s * L_ + l0 + c0];
        *(float2*)&logits[((size_t)kh * NQ_ + qq) * L_ + l0 + c0] =
            make_float2(acc[i][0] + m2.x, acc[i][1] + m2.y);
    }
}

// ---------------- Kernel D: row stats (online max + sum) ----------------
__global__ __launch_bounds__(256) void k_rowstat(
    const float* __restrict__ logits,
    float* __restrict__ rowmax, float* __restrict__ rowsum)
{
    const int r = blockIdx.x;
    const int tid = threadIdx.x;
    const float* lp = logits + (size_t)r * L_;
    float m = -1e30f, s = 0.f;
    for (int i = tid; i < L_; i += 256) {
        float x = lp[i];
        float nm = fmaxf(m, x);
        s = s * __expf(m - nm) + __expf(x - nm);
        m = nm;
    }
    #pragma unroll
    for (int off = 32; off; off >>= 1) {
        float m2 = __shfl_xor(m, off, 64);
        float s2 = __shfl_xor(s, off, 64);
        float nm = fmaxf(m, m2);
        s = s * __expf(m - nm) + s2 * __expf(m2 - nm);
        m = nm;
    }
    __shared__ float rm[4], rs[4];
    if ((tid & 63) == 0) { rm[tid >> 6] = m; rs[tid >> 6] = s; }
    __syncthreads();
    if (tid == 0) {
        float M = fmaxf(fmaxf(rm[0], rm[1]), fmaxf(rm[2], rm[3]));
        float S = rs[0] * __expf(rm[0] - M) + rs[1] * __expf(rm[1] - M)
                + rs[2] * __expf(rm[2] - M) + rs[3] * __expf(rm[3] - M);
        rowmax[r] = M;
        rowsum[r] = S;
    }
}

// ---------------- Kernel E: PV partial, block-owned L-chunks ----------------
// grid (64 chunks of 128, 4 kv), block 512. pvpart[kh][chunk][64][256]. V double-buffered.
__global__ __launch_bounds__(512) void k_pv(
    const float* __restrict__ logits,
    const float* __restrict__ rowmax,
    const float* __restrict__ cache_v, const float* __restrict__ vnb,
    float* __restrict__ pvpart)
{
    const int l0 = blockIdx.x * 128;
    const int kh = blockIdx.y;
    const int tid = threadIdx.x;
    const int r0 = (tid >> 6) * 8;      // wave-uniform 8 q-rows
    const int c0 = (tid & 63) * 4;      // 4 d-cols

    __shared__ __align__(16) float ps[64][132];      // [q][l] exp'd
    __shared__ __align__(16) float vs[2][16][260];   // [buf][l][d]

    // stage P tile with exp: 2048 float4
    #pragma unroll
    for (int i = 0; i < 4; i++) {
        int idx = i * 512 + tid;
        int qq = idx >> 5, lq = idx & 31;
        float4 v = *(const float4*)&logits[((size_t)kh * NQ_ + qq) * L_ + l0 + lq * 4];
        float rm = rowmax[kh * NQ_ + qq];
        v.x = __expf(v.x - rm); v.y = __expf(v.y - rm);
        v.z = __expf(v.z - rm); v.w = __expf(v.w - rm);
        *(float4*)&ps[qq][lq * 4] = v;
    }
    // stage V chunk 0
    #pragma unroll
    for (int i = 0; i < 2; i++) {
        int idx = i * 512 + tid;
        int l = idx >> 6, dq = idx & 63;
        int labs = l0 + l;
        const float* src = (labs < LKEEP_)
            ? (cache_v + ((size_t)kh * L_ + labs + S_) * 256 + dq * 4)
            : (vnb + ((size_t)kh * S_ + (labs - LKEEP_)) * 256 + dq * 4);
        *(float4*)&vs[0][l][dq * 4] = *(const float4*)src;
    }
    __syncthreads();

    float acc[8][4] = {};
    for (int lc = 0; lc < 8; lc++) {
        const int cur = lc & 1, nxt = cur ^ 1;
        if (lc < 7) {
            #pragma unroll
            for (int i = 0; i < 2; i++) {
                int idx = i * 512 + tid;
                int l = idx >> 6, dq = idx & 63;
                int labs = l0 + (lc + 1) * 16 + l;
                const float* src = (labs < LKEEP_)
                    ? (cache_v + ((size_t)kh * L_ + labs + S_) * 256 + dq * 4)
                    : (vnb + ((size_t)kh * S_ + (labs - LKEEP_)) * 256 + dq * 4);
                *(float4*)&vs[nxt][l][dq * 4] = *(const float4*)src;
            }
        }
        #pragma unroll
        for (int lg = 0; lg < 4; lg++) {
            float4 pv[8];
            #pragma unroll
            for (int i = 0; i < 8; i++)
                pv[i] = *(const float4*)&ps[r0 + i][lc * 16 + lg * 4];  // broadcast
            float4 v0 = *(const float4*)&vs[cur][lg * 4 + 0][c0];
            float4 v1 = *(const float4*)&vs[cur][lg * 4 + 1][c0];
            float4 v2 = *(const float4*)&vs[cur][lg * 4 + 2][c0];
            float4 v3 = *(const float4*)&vs[cur][lg * 4 + 3][c0];
            #pragma unroll
            for (int i = 0; i < 8; i++) {
                acc[i][0] = fmaf(pv[i].x, v0.x, acc[i][0]); acc[i][1] = fmaf(pv[i].x, v0.y, acc[i][1]);
                acc[i][2] = fmaf(pv[i].x, v0.z, acc[i][2]); acc[i][3] = fmaf(pv[i].x, v0.w, acc[i][3]);
                acc[i][0] = fmaf(pv[i].y, v1.x, acc[i][0]); acc[i][1] = fmaf(pv[i].y, v1.y, acc[i][1]);
                acc[i][2] = fmaf(pv[i].y, v1.z, acc[i][2]); acc[i][3] = fmaf(pv[i].y, v1.w, acc[i][3]);
                acc[i][0] = fmaf(pv[i].z, v2.x, acc[i][0]); acc[i][1] = fmaf(pv[i].z, v2.y, acc[i][1]);
                acc[i][2] = fmaf(pv[i].z, v2.z, acc[i][2]); acc[i][3] = fmaf(pv[i].z, v2.w, acc[i][3]);
                acc[i][0] = fmaf(pv[i].w, v3.x, acc[i][0]); acc[i][1] = fmaf(pv[i].w, v3.y, acc[i][1]);
                acc[i][2] = fmaf(pv[i].w, v3.z, acc[i][2]); acc[i][3] = fmaf(pv[i].w, v3.w, acc[i][3]);
            }
        }
        __syncthreads();
    }
    float* op = pvpart + (((size_t)kh * 64 + blockIdx.x) * NQ_) * 256;
    #pragma unroll
    for (int i = 0; i < 8; i++)
        *(float4*)&op[(r0 + i) * 256 + c0] =
            make_float4(acc[i][0], acc[i][1], acc[i][2], acc[i][3]);
}

// ---------------- Kernel F: combine 64 PV partials + normalize + interleave ----------------
__global__ __launch_bounds__(256) void k_pvcomb(
    const float* __restrict__ pvpart, const float* __restrict__ rowsum,
    float* __restrict__ attn)
{
    const int b = blockIdx.x;           // kh*64 + n
    const int kh = b >> 6, n = b & 63;
    const int d = threadIdx.x;
    const float* pp = pvpart + ((size_t)kh * 64 * NQ_ + n) * 256 + d;
    float s0 = 0.f, s1 = 0.f, s2 = 0.f, s3 = 0.f;
    for (int c = 0; c < 64; c += 4) {
        s0 += pp[(size_t)(c + 0) * (NQ_ * 256)];
        s1 += pp[(size_t)(c + 1) * (NQ_ * 256)];
        s2 += pp[(size_t)(c + 2) * (NQ_ * 256)];
        s3 += pp[(size_t)(c + 3) * (NQ_ * 256)];
    }
    float sum = (s0 + s1) + (s2 + s3);
    const int h = kh * 2 + (n >> 5), s = n & 31;
    attn[(size_t)s * 2048 + h * 256 + d] = sum / rowsum[b];
}

// ---------------- Kernel G: W_o GEMM, K-split x32 into partials ----------------
// grid (5 col-tiles of 512, 32 k-splits of 64), block 256. Race-free full-k per thread.
__global__ __launch_bounds__(256) void k_out(
    const float* __restrict__ attn, const float* __restrict__ Wo,
    float* __restrict__ opart)
{
    const int col0  = blockIdx.x * 512;
    const int kbase = blockIdx.y * 64;
    const int tid   = threadIdx.x;
    const int tc    = tid * 2;

    __shared__ __align__(16) float hsT[64][36];
    #pragma unroll
    for (int i = 0; i < 2; i++) {
        int idx = i * 256 + tid;            // 512 float4 = 32r x 16c4
        int r = idx >> 4, c4 = idx & 15;
        float4 v = *(const float4*)&attn[r * 2048 + kbase + c4 * 4];
        hsT[c4*4+0][r] = v.x; hsT[c4*4+1][r] = v.y;
        hsT[c4*4+2][r] = v.z; hsT[c4*4+3][r] = v.w;
    }
    __syncthreads();

    const float* Wt = Wo + (size_t)kbase * 2560 + col0 + tc;
    float acc[32][2] = {};
#define LW(k) (*(const float2*)&Wt[(size_t)(k) * 2560])
#define FMABLK(k, wc) \
    _Pragma("unroll") for (int r4 = 0; r4 < 8; r4++) { \
      float4 h = *(const float4*)&hsT[(k)][r4*4]; \
      acc[r4*4+0][0] = fmaf(h.x, wc.x, acc[r4*4+0][0]); acc[r4*4+0][1] = fmaf(h.x, wc.y, acc[r4*4+0][1]); \
      acc[r4*4+1][0] = fmaf(h.y, wc.x, acc[r4*4+1][0]); acc[r4*4+1][1] = fmaf(h.y, wc.y, acc[r4*4+1][1]); \
      acc[r4*4+2][0] = fmaf(h.z, wc.x, acc[r4*4+2][0]); acc[r4*4+2][1] = fmaf(h.z, wc.y, acc[r4*4+2][1]); \
      acc[r4*4+3][0] = fmaf(h.w, wc.x, acc[r4*4+3][0]); acc[r4*4+3][1] = fmaf(h.w, wc.y, acc[r4*4+3][1]); }
#define STEPL(wreg, k) { float2 wc = wreg; wreg = LW((k) + 8); FMABLK(k, wc) }
#define STEPN(wreg, k) { float2 wc = wreg; FMABLK(k, wc) }

    float2 w0=LW(0),w1=LW(1),w2=LW(2),w3=LW(3),w4=LW(4),w5=LW(5),w6=LW(6),w7=LW(7);
    for (int ib = 0; ib <= 48; ib += 8) {     // k = 0..55, prefetch k+8 <= 63
        STEPL(w0, ib+0) STEPL(w1, ib+1) STEPL(w2, ib+2) STEPL(w3, ib+3)
        STEPL(w4, ib+4) STEPL(w5, ib+5) STEPL(w6, ib+6) STEPL(w7, ib+7)
    }
    STEPN(w0, 56) STEPN(w1, 57) STEPN(w2, 58) STEPN(w3, 59)
    STEPN(w4, 60) STEPN(w5, 61) STEPN(w6, 62) STEPN(w7, 63)
#undef STEPL
#undef STEPN
#undef FMABLK
#undef LW
    float* op = opart + (size_t)blockIdx.y * (32 * 2560);
    #pragma unroll
    for (int r = 0; r < 32; r++)
        *(float2*)&op[r * 2560 + col0 + tc] = make_float2(acc[r][0], acc[r][1]);
}

// ---------------- Kernel H: sum 32 W_o partials into d_out ----------------
__global__ __launch_bounds__(256) void k_osum(const float* __restrict__ opart,
                                              float* __restrict__ out)
{
    int idx = blockIdx.x * 256 + threadIdx.x;   // 320 blocks -> 81920
    float a0 = 0.f, a1 = 0.f, a2 = 0.f, a3 = 0.f;
    #pragma unroll
    for (int p = 0; p < 32; p += 4) {
        a0 += opart[(size_t)(p + 0) * 81920 + idx];
        a1 += opart[(size_t)(p + 1) * 81920 + idx];
        a2 += opart[(size_t)(p + 2) * 81920 + idx];
        a3 += opart[(size_t)(p + 3) * 81920 + idx];
    }
    out[idx] = (a0 + a1) + (a2 + a3);
}

// ---------------- host ----------------
extern "C" void kernel_launch(void* const* d_in, const int* in_sizes, int n_in,
                              void* d_out, int out_size, void* d_ws, size_t ws_size,
                              hipStream_t stream)
{
    const float* hidden  = (const float*)d_in[0];
    const float* cosb    = (const float*)d_in[1];
    const float* sinb    = (const float*)d_in[2];
    const float* cache_k = (const float*)d_in[3];
    const float* cache_v = (const float*)d_in[4];
    const float* mask    = (const float*)d_in[5];
    const float* Wq      = (const float*)d_in[6];
    const float* Wk      = (const float*)d_in[7];
    const float* Wv      = (const float*)d_in[8];
    const float* Wo      = (const float*)d_in[9];
    const float* qw      = (const float*)d_in[10];
    const float* kw      = (const float*)d_in[11];
    const float* vw      = (const float*)d_in[12];

    float* ws = (float*)d_ws;
    // Region A (4,194,304 floats) time-shared: qkv partials -> pv partials -> Wo partials
    float* A      = ws;
    float* logits = ws + 4194304;           // 2,097,152
    float* qb     = ws + 6291456;           // 65,536
    float* knb    = ws + 6356992;           // 32,768
    float* vnb    = ws + 6389760;           // 32,768
    float* rowmax = ws + 6422528;           // 256
    float* rowsum = ws + 6422784;           // 256
    float* attn   = ws + 6423040;           // 65,536  (ws total ~25.9 MB)

    float* qkvp   = A;      // [32][32][4096]
    float* pvpart = A;      // [4][64][64][256]
    float* opart  = A;      // [32][32][2560]

    k_qkv<<<dim3(8, 32), 256, 0, stream>>>(hidden, Wq, Wk, Wv, qkvp);
    k_rms_rope<<<512, 256, 0, stream>>>(qkvp, cosb, sinb, qw, kw, vw, qb, knb, vnb);
    k_qk<<<dim3(64, 4), 512, 0, stream>>>(qb, cache_k, knb, mask, logits);
    k_rowstat<<<256, 256, 0, stream>>>(logits, rowmax, rowsum);
    k_pv<<<dim3(64, 4), 512, 0, stream>>>(logits, rowmax, cache_v, vnb, pvpart);
    k_pvcomb<<<256, 256, 0, stream>>>(pvpart, rowsum, attn);
    k_out<<<dim3(5, 32), 256, 0, stream>>>(attn, Wo, opart);
    k_osum<<<320, 256, 0, stream>>>(opart, (float*)d_out);
}